// Round 7
// baseline (141.040 us; speedup 1.0000x reference)
//
#include <hip/hip_runtime.h>
#include <hip/hip_bf16.h>

#define B_    32
#define T_    12
#define TM1   11
#define K_    16
#define DIM_  512
#define H0_   512
#define H1_   256
#define NROWS 5632
#define NBT   352
#define E_ELEMS (NBT*256*H1_)

typedef __bf16 bf16x8 __attribute__((ext_vector_type(8)));
typedef float  f32x16 __attribute__((ext_vector_type(16)));
typedef unsigned u32x4 __attribute__((ext_vector_type(4)));

#define OFRAG_OFF   0
#define W0FRAG_OFF  5767168
#define W1FRAG_OFF  (W0FRAG_OFF + 1048576)
#define UB_OFF      (W1FRAG_OFF + 262144)
#define VSW_OFF     (UB_OFF + 5767168)

__device__ __forceinline__ unsigned bf_rn(float f) {
    unsigned u = __float_as_uint(f);
    return (u + 0x7fffu + ((u >> 16) & 1u)) >> 16;
}
__device__ __forceinline__ unsigned pk_bf16(float lo, float hi) {
    return bf_rn(lo) | (bf_rn(hi) << 16);
}
__device__ __forceinline__ unsigned short f2bf(float f) {
    return (unsigned short)bf_rn(f);
}
__device__ __forceinline__ float bfu_lo(unsigned u) { return __uint_as_float(u << 16); }
__device__ __forceinline__ float bfu_hi(unsigned u) { return __uint_as_float(u & 0xffff0000u); }
__device__ __forceinline__ unsigned cvt_pk(float lo, float hi) {
    unsigned r;
    asm("v_cvt_pk_bf16_f32 %0, %1, %2" : "=v"(r) : "v"(lo), "v"(hi));
    return r;
}

// ---------------------------------------------------------------------------
// k_prep: merged W0/W1/O fragment repack (bf16, fragment-ordered).
// ---------------------------------------------------------------------------
__global__ __launch_bounds__(256) void k_prep(const float* __restrict__ W0,
                                              const float* __restrict__ W1,
                                              const float* __restrict__ O,
                                              char* __restrict__ ws)
{
    const int unit = blockIdx.x * 4 + (threadIdx.x >> 6);
    const int l = threadIdx.x & 63;
    if (unit < 1280) {
        const float* src; size_t dstoff; int stride;
        if (unit < 1024) {
            int half = unit >> 9, s = (unit >> 4) & 31, nt = unit & 15;
            int k = s*16 + (l >> 5)*8;
            int n = nt*32 + (l & 31);
            src = W0 + (size_t)(half*512 + k) * H0_ + n;
            stride = H0_;
            dstoff = W0FRAG_OFF + (((size_t)(half*32 + s)*16 + nt)*64 + l)*16;
        } else {
            int r = unit - 1024; int s = r >> 3, ct = r & 7;
            int k = s*16 + (l >> 5)*8;
            int n = ct*32 + (l & 31);
            src = W1 + (size_t)k * H1_ + n;
            stride = H1_;
            dstoff = W1FRAG_OFF + (((size_t)(s*8 + ct))*64 + l)*16;
        }
        float f[8];
        #pragma unroll
        for (int j = 0; j < 8; ++j) f[j] = src[(size_t)j * stride];
        u32x4 o = { pk_bf16(f[0],f[1]), pk_bf16(f[2],f[3]), pk_bf16(f[4],f[5]), pk_bf16(f[6],f[7]) };
        *(u32x4*)(ws + dstoff) = o;
    } else {
        const int u = unit - 1280;
        const int s = u / 176, mt = u % 176;
        const int row = mt*32 + (l & 31);
        const int b  = row / (TM1*K_);
        const int rem = row % (TM1*K_);
        const int t  = rem / K_;
        const int i  = rem % K_;
        const float* src = O + (((size_t)(b*T_ + t + 1)*K_ + i)*DIM_) + s*16 + (l >> 5)*8;
        float4 a = *(const float4*)src;
        float4 c = *(const float4*)(src + 4);
        u32x4 o = { pk_bf16(a.x,a.y), pk_bf16(a.z,a.w), pk_bf16(c.x,c.y), pk_bf16(c.z,c.w) };
        *(u32x4*)(ws + OFRAG_OFF + ((size_t)(s*176 + mt)*64 + l)*16) = o;
    }
}

// ---------------------------------------------------------------------------
// k_uv (unchanged from R5)
// ---------------------------------------------------------------------------
__global__ __launch_bounds__(256) void k_uv(char* __restrict__ ws,
                                            const float* __restrict__ b0)
{
    const int mb = blockIdx.x;
    const int t  = threadIdx.x, l = t & 63;
    const int nb = blockIdx.y * 4 + (t >> 6);
    const int half = nb >> 3;
    const char* Ag = ws + OFRAG_OFF + ((size_t)(mb*2)*64 + l)*16;
    const char* Bg = ws + W0FRAG_OFF + (size_t)half*524288 + ((size_t)((nb&7)*2)*64 + l)*16;
    const size_t AS = 176*1024, BS = 16*1024;

    f32x16 acc[2][2];
    #pragma unroll
    for (int p = 0; p < 2; ++p)
        #pragma unroll
        for (int c = 0; c < 2; ++c)
            #pragma unroll
            for (int r = 0; r < 16; ++r) acc[p][c][r] = 0.f;

    u32x4 aA[2], bA[2], aB[2], bB[2];
    #pragma unroll
    for (int p = 0; p < 2; ++p) {
        aA[p] = *(const u32x4*)(Ag + 0*AS + p*1024);
        bA[p] = *(const u32x4*)(Bg + 0*BS + p*1024);
        aB[p] = *(const u32x4*)(Ag + 1*AS + p*1024);
        bB[p] = *(const u32x4*)(Bg + 1*BS + p*1024);
    }

    for (int ss = 0; ss < 32; ss += 2) {
        {
            union { u32x4 u[2]; bf16x8 b[2]; } af, bf;
            af.u[0]=aA[0]; af.u[1]=aA[1]; bf.u[0]=bA[0]; bf.u[1]=bA[1];
            if (ss + 2 < 32) {
                #pragma unroll
                for (int p = 0; p < 2; ++p) {
                    aA[p] = *(const u32x4*)(Ag + (size_t)(ss+2)*AS + p*1024);
                    bA[p] = *(const u32x4*)(Bg + (size_t)(ss+2)*BS + p*1024);
                }
            }
            acc[0][0] = __builtin_amdgcn_mfma_f32_32x32x16_bf16(af.b[0], bf.b[0], acc[0][0], 0,0,0);
            acc[0][1] = __builtin_amdgcn_mfma_f32_32x32x16_bf16(af.b[0], bf.b[1], acc[0][1], 0,0,0);
            acc[1][0] = __builtin_amdgcn_mfma_f32_32x32x16_bf16(af.b[1], bf.b[0], acc[1][0], 0,0,0);
            acc[1][1] = __builtin_amdgcn_mfma_f32_32x32x16_bf16(af.b[1], bf.b[1], acc[1][1], 0,0,0);
        }
        {
            union { u32x4 u[2]; bf16x8 b[2]; } af, bf;
            af.u[0]=aB[0]; af.u[1]=aB[1]; bf.u[0]=bB[0]; bf.u[1]=bB[1];
            if (ss + 3 < 32) {
                #pragma unroll
                for (int p = 0; p < 2; ++p) {
                    aB[p] = *(const u32x4*)(Ag + (size_t)(ss+3)*AS + p*1024);
                    bB[p] = *(const u32x4*)(Bg + (size_t)(ss+3)*BS + p*1024);
                }
            }
            acc[0][0] = __builtin_amdgcn_mfma_f32_32x32x16_bf16(af.b[0], bf.b[0], acc[0][0], 0,0,0);
            acc[0][1] = __builtin_amdgcn_mfma_f32_32x32x16_bf16(af.b[0], bf.b[1], acc[0][1], 0,0,0);
            acc[1][0] = __builtin_amdgcn_mfma_f32_32x32x16_bf16(af.b[1], bf.b[0], acc[1][0], 0,0,0);
            acc[1][1] = __builtin_amdgcn_mfma_f32_32x32x16_bf16(af.b[1], bf.b[1], acc[1][1], 0,0,0);
        }
    }

    #pragma unroll
    for (int p = 0; p < 2; ++p) {
        #pragma unroll
        for (int c = 0; c < 2; ++c) {
            const int col = (nb & 7)*64 + c*32 + (l & 31);
            const float bias = (half == 0) ? b0[col] : 0.f;
            #pragma unroll
            for (int r = 0; r < 16; ++r) {
                const int row = (r & 3) + 8*(r >> 2) + 4*(l >> 5);
                const int M = mb*64 + p*32 + row;
                const float v = acc[p][c][r] + bias;
                if (half == 0) {
                    *(unsigned short*)(ws + UB_OFF + ((size_t)M*512 + col)*2) = f2bf(v);
                } else {
                    const int bt = M >> 4, j = M & 15;
                    const int cc = col >> 3;
                    const int c2 = ((cc ^ (j & 7)) << 3) | (col & 7);
                    *(unsigned short*)(ws + VSW_OFF + ((size_t)(bt*16 + j)*512 + c2)*2) = f2bf(v);
                }
            }
        }
    }
}

// ---------------------------------------------------------------------------
// k_obj (unchanged)
// ---------------------------------------------------------------------------
__global__ __launch_bounds__(256) void k_obj(const float* __restrict__ O,
                                             float* __restrict__ out)
{
    __shared__ float red[16][16];
    __shared__ float fl[16];
    const int bt = blockIdx.x;
    const int b_ = bt / TM1, tt = bt % TM1;
    const int t  = threadIdx.x;
    const int i  = t >> 4, s = t & 15;
    const float* base = O + (((size_t)(b_ * T_ + tt + 1) * K_ + i) * DIM_) + s * 32;
    float sum = 0.f;
    #pragma unroll
    for (int q = 0; q < 8; ++q) {
        float4 v = *(const float4*)(base + q * 4);
        sum += v.x + v.y + v.z + v.w;
    }
    red[i][s] = sum;
    __syncthreads();
    if (t < 16) {
        float f = 0.f;
        #pragma unroll
        for (int s2 = 0; s2 < 16; ++s2) f += red[t][s2];
        fl[t] = fminf(fmaxf(f, 0.f), 1.f);
    }
    __syncthreads();
    const float val = fminf((float)(tt + 1) * fl[t >> 4] * fl[t & 15], 1.f);
    __builtin_nontemporal_store(val, out + (size_t)E_ELEMS + (size_t)bt * 256 + t);
}

// ---------------------------------------------------------------------------
// DIAGNOSTIC k_e variants. MODE: 0 = full compute, no out stores (checksum only)
//                                1 = 0 minus h-build (afrag := raw U bits)
//                                2 = 0 minus W1 global loads (const B operand)
//                                3 = pure MFMA chain (no LDS, no loads)
// Writes 1 dword/thread checksum into dead ws scrap (Ofrag region — nothing
// reads Ofrag after k_uv, and k_prep fully rewrites it each launch).
// ---------------------------------------------------------------------------
template<int MODE>
__global__ __launch_bounds__(256, 2) void k_e_diag(const char* __restrict__ ws,
                                                   char* __restrict__ scrap)
{
    __shared__ alignas(16) char lds[24576];
    char* Us = lds;
    char* Vs = lds + 8192;

    const int bid = blockIdx.x;
    const int bt = bid >> 1, ph = bid & 1;
    const int t = threadIdx.x, l = t & 63, w = t >> 6;
    const int wp = w & 1, wc = w >> 1;

    const char* Ug = ws + UB_OFF  + (size_t)(bt*16 + ph*8) * 1024;
    const char* Vg = ws + VSW_OFF + (size_t)bt * 16384;
    const char* Wg = ws + W1FRAG_OFF + (size_t)(wc*4)*1024 + (size_t)l*16;

    if (MODE < 3) {
        #pragma unroll
        for (int r = 0; r < 2; ++r) { int c = t + r*256; *(u32x4*)(Us + c*16) = *(const u32x4*)(Ug + c*16); }
        #pragma unroll
        for (int r = 0; r < 4; ++r) { int c = t + r*256; *(u32x4*)(Vs + c*16) = *(const u32x4*)(Vg + c*16); }
        __syncthreads();
    }

    f32x16 acc[2][4];
    #pragma unroll
    for (int p = 0; p < 2; ++p)
        #pragma unroll
        for (int c = 0; c < 4; ++c)
            #pragma unroll
            for (int r = 0; r < 16; ++r) acc[p][c][r] = 0.f;

    const int jj = l & 15;
    const int kc = l >> 5;
    const int ih = (l >> 4) & 1;

    u32x4 wn[4];
    if (MODE != 2 && MODE != 3) {
        #pragma unroll
        for (int c = 0; c < 4; ++c) wn[c] = *(const u32x4*)(Wg + c*1024);
    } else {
        #pragma unroll
        for (int c = 0; c < 4; ++c) wn[c] = u32x4{0x3f803f80u + (unsigned)t, 0x3f803f80u, 0x3f803f80u, 0x3f803f80u};
    }

    for (int s = 0; s < 32; ++s) {
        union { u32x4 u[4]; bf16x8 b[4]; } wcur;
        #pragma unroll
        for (int c = 0; c < 4; ++c) wcur.u[c] = wn[c];
        if (MODE != 2 && MODE != 3 && s < 31) {
            #pragma unroll
            for (int c = 0; c < 4; ++c)
                wn[c] = *(const u32x4*)(Wg + (size_t)(s+1)*8192 + c*1024);
        }

        bf16x8 afrag[2];
        if (MODE == 3) {
            union { u32x4 u; bf16x8 b; } cv;
            cv.u = u32x4{0x3f803f80u ^ (unsigned)(t + s), 0x3f803f80u, 0x3f803f80u, 0x3f803f80u};
            afrag[0] = cv.b; afrag[1] = cv.b;
        } else if (MODE == 1) {
            #pragma unroll
            for (int p = 0; p < 2; ++p) {
                const int iloc = wp*4 + p*2 + ih;
                union { u32x4 u; bf16x8 b; } cv;
                cv.u = *(const u32x4*)(Us + iloc*1024 + s*32 + kc*16);
                afrag[p] = cv.b;
            }
        } else {
            const int vchunk = (s*2 + kc) ^ (jj & 7);
            u32x4 vu = *(const u32x4*)(Vs + jj*1024 + vchunk*16);
            float vf[8];
            #pragma unroll
            for (int q = 0; q < 4; ++q) { vf[2*q] = bfu_lo(vu[q]); vf[2*q+1] = bfu_hi(vu[q]); }
            #pragma unroll
            for (int p = 0; p < 2; ++p) {
                const int iloc = wp*4 + p*2 + ih;
                u32x4 uu = *(const u32x4*)(Us + iloc*1024 + s*32 + kc*16);
                u32x4 o;
                #pragma unroll
                for (int q = 0; q < 4; ++q) {
                    float h0 = fmaxf(bfu_lo(uu[q]) + vf[2*q],   0.f);
                    float h1 = fmaxf(bfu_hi(uu[q]) + vf[2*q+1], 0.f);
                    o[q] = cvt_pk(h0, h1);
                }
                union { u32x4 u; bf16x8 b; } cv; cv.u = o;
                afrag[p] = cv.b;
            }
        }

        #pragma unroll
        for (int p = 0; p < 2; ++p)
            #pragma unroll
            for (int c = 0; c < 4; ++c)
                acc[p][c] = __builtin_amdgcn_mfma_f32_32x32x16_bf16(afrag[p], wcur.b[c], acc[p][c], 0, 0, 0);
    }

    float sum = 0.f;
    #pragma unroll
    for (int p = 0; p < 2; ++p)
        #pragma unroll
        for (int c = 0; c < 4; ++c)
            #pragma unroll
            for (int r = 0; r < 16; ++r) sum += acc[p][c][r];
    *(float*)(scrap + ((size_t)bid*256 + t)*4) = sum;
}

// ---------------------------------------------------------------------------
// k_e (real): EXACT R5 version (known-pass). Barrier-free main loop, depth-2
// W1 register pipeline (4 rotating banks), nt output stores.
// ---------------------------------------------------------------------------
#define EBODY(S, WUSE, WLD, DOLOAD)                                            \
    do {                                                                       \
        if (DOLOAD) {                                                          \
            _Pragma("unroll")                                                  \
            for (int c_ = 0; c_ < 4; ++c_)                                     \
                WLD[c_] = *(const u32x4*)(Wg + (size_t)((S)+2)*8192 + c_*1024);\
        }                                                                      \
        const int vchunk_ = ((S)*2 + kc) ^ (jj & 7);                           \
        u32x4 vu_ = *(const u32x4*)(Vs + jj*1024 + vchunk_*16);                \
        float vf_[8];                                                          \
        _Pragma("unroll")                                                      \
        for (int q_ = 0; q_ < 4; ++q_) {                                       \
            vf_[2*q_] = bfu_lo(vu_[q_]); vf_[2*q_+1] = bfu_hi(vu_[q_]);        \
        }                                                                      \
        bf16x8 afrag_[2];                                                      \
        _Pragma("unroll")                                                      \
        for (int p_ = 0; p_ < 2; ++p_) {                                       \
            const int iloc_ = wp*4 + p_*2 + ih;                                \
            u32x4 uu_ = *(const u32x4*)(Us + iloc_*1024 + (S)*32 + kc*16);     \
            u32x4 o_;                                                          \
            _Pragma("unroll")                                                  \
            for (int q_ = 0; q_ < 4; ++q_) {                                   \
                float h0_ = fmaxf(bfu_lo(uu_[q_]) + vf_[2*q_],   0.f);         \
                float h1_ = fmaxf(bfu_hi(uu_[q_]) + vf_[2*q_+1], 0.f);         \
                o_[q_] = cvt_pk(h0_, h1_);                                     \
            }                                                                  \
            union { u32x4 u; bf16x8 b; } cv_; cv_.u = o_; afrag_[p_] = cv_.b;  \
        }                                                                      \
        union { u32x4 u[4]; bf16x8 b[4]; } wcu_;                               \
        _Pragma("unroll")                                                      \
        for (int c_ = 0; c_ < 4; ++c_) wcu_.u[c_] = WUSE[c_];                  \
        _Pragma("unroll")                                                      \
        for (int p_ = 0; p_ < 2; ++p_)                                         \
            _Pragma("unroll")                                                  \
            for (int c_ = 0; c_ < 4; ++c_)                                     \
                acc[p_][c_] = __builtin_amdgcn_mfma_f32_32x32x16_bf16(         \
                    afrag_[p_], wcu_.b[c_], acc[p_][c_], 0, 0, 0);             \
    } while (0)

__global__ __launch_bounds__(256, 2) void k_e(const char* __restrict__ ws,
                                              const float* __restrict__ b1,
                                              float* __restrict__ out)
{
    __shared__ alignas(16) char lds[24576];
    char* Us = lds;
    char* Vs = lds + 8192;

    const int bid = blockIdx.x;
    const int bt = bid >> 1, ph = bid & 1;
    const int t = threadIdx.x, l = t & 63, w = t >> 6;
    const int wp = w & 1, wc = w >> 1;

    const char* Ug = ws + UB_OFF  + (size_t)(bt*16 + ph*8) * 1024;
    const char* Vg = ws + VSW_OFF + (size_t)bt * 16384;
    const char* Wg = ws + W1FRAG_OFF + (size_t)(wc*4)*1024 + (size_t)l*16;

    #pragma unroll
    for (int r = 0; r < 2; ++r) { int c = t + r*256; *(u32x4*)(Us + c*16) = *(const u32x4*)(Ug + c*16); }
    #pragma unroll
    for (int r = 0; r < 4; ++r) { int c = t + r*256; *(u32x4*)(Vs + c*16) = *(const u32x4*)(Vg + c*16); }
    __syncthreads();

    f32x16 acc[2][4];
    #pragma unroll
    for (int p = 0; p < 2; ++p)
        #pragma unroll
        for (int c = 0; c < 4; ++c)
            #pragma unroll
            for (int r = 0; r < 16; ++r) acc[p][c][r] = 0.f;

    const int jj = l & 15;
    const int kc = l >> 5;
    const int ih = (l >> 4) & 1;

    u32x4 wk0[4], wk1[4], wk2[4], wk3[4];
    #pragma unroll
    for (int c = 0; c < 4; ++c) wk0[c] = *(const u32x4*)(Wg + c*1024);
    #pragma unroll
    for (int c = 0; c < 4; ++c) wk1[c] = *(const u32x4*)(Wg + 8192 + c*1024);

    for (int j = 0; j < 8; ++j) {
        const int s = j * 4;
        EBODY(s+0, wk0, wk2, true);
        EBODY(s+1, wk1, wk3, true);
        EBODY(s+2, wk2, wk0, (j < 7));
        EBODY(s+3, wk3, wk1, (j < 7));
    }

    #pragma unroll
    for (int c = 0; c < 4; ++c) {
        const int col = wc*128 + c*32 + (l & 31);
        const float bb = b1[col];
        #pragma unroll
        for (int p = 0; p < 2; ++p) {
            #pragma unroll
            for (int r = 0; r < 16; ++r) {
                const int pair = ph*128 + wp*64 + p*32 + (r & 3) + 8*(r >> 2) + 4*(l >> 5);
                const float v = fmaxf(acc[p][c][r] + bb, 0.f);
                __builtin_nontemporal_store(v, out + ((size_t)bt*256 + pair)*256 + col);
            }
        }
    }
}

// ---------------------------------------------------------------------------
extern "C" void kernel_launch(void* const* d_in, const int* in_sizes, int n_in,
                              void* d_out, int out_size, void* d_ws, size_t ws_size,
                              hipStream_t stream) {
    const float* O  = (const float*)d_in[0];
    const float* W0 = (const float*)d_in[1];
    const float* b0 = (const float*)d_in[2];
    const float* W1 = (const float*)d_in[3];
    const float* b1 = (const float*)d_in[4];
    float* out = (float*)d_out;
    char* ws = (char*)d_ws;

    k_prep<<<1728, 256, 0, stream>>>(W0, W1, O, ws);
    dim3 guv(88, 4);
    k_uv<<<guv, 256, 0, stream>>>(ws, b0);
    k_obj<<<NBT, 256, 0, stream>>>(O, out);

    // --- diagnostics (write only to dead Ofrag scrap; before real k_e) ---
    char* scrap = ws + OFRAG_OFF;
    k_e_diag<0><<<NBT * 2, 256, 0, stream>>>(ws, scrap);
    k_e_diag<1><<<NBT * 2, 256, 0, stream>>>(ws, scrap);
    k_e_diag<2><<<NBT * 2, 256, 0, stream>>>(ws, scrap);
    k_e_diag<3><<<NBT * 2, 256, 0, stream>>>(ws, scrap);

    k_e<<<NBT * 2, 256, 0, stream>>>(ws, b1, out);
}

// Round 9
// 70.893 us; speedup vs baseline: 1.9895x; 1.9895x over previous
//
#include <hip/hip_runtime.h>
#include <hip/hip_bf16.h>

#define B_    32
#define T_    12
#define TM1   11
#define K_    16
#define DIM_  512
#define H0_   512
#define H1_   256
#define NROWS 5632
#define NBT   352
#define E_ELEMS (NBT*256*H1_)

typedef __bf16 bf16x8 __attribute__((ext_vector_type(8)));
typedef float  f32x16 __attribute__((ext_vector_type(16)));
typedef float  f32x4  __attribute__((ext_vector_type(4)));
typedef unsigned u32x4 __attribute__((ext_vector_type(4)));

#define OFRAG_OFF   0
#define W0FRAG_OFF  5767168
#define W1FRAG_OFF  (W0FRAG_OFF + 1048576)
#define UB_OFF      (W1FRAG_OFF + 262144)
#define VSW_OFF     (UB_OFF + 5767168)

__device__ __forceinline__ unsigned bf_rn(float f) {
    unsigned u = __float_as_uint(f);
    return (u + 0x7fffu + ((u >> 16) & 1u)) >> 16;
}
__device__ __forceinline__ unsigned pk_bf16(float lo, float hi) {
    return bf_rn(lo) | (bf_rn(hi) << 16);
}
__device__ __forceinline__ unsigned short f2bf(float f) {
    return (unsigned short)bf_rn(f);
}
__device__ __forceinline__ float bfu_lo(unsigned u) { return __uint_as_float(u << 16); }
__device__ __forceinline__ float bfu_hi(unsigned u) { return __uint_as_float(u & 0xffff0000u); }
__device__ __forceinline__ unsigned cvt_pk(float lo, float hi) {
    unsigned r;
    asm("v_cvt_pk_bf16_f32 %0, %1, %2" : "=v"(r) : "v"(lo), "v"(hi));
    return r;
}

// ---------------------------------------------------------------------------
// k_prep: merged W0/W1/O fragment repack (bf16, fragment-ordered).
// ---------------------------------------------------------------------------
__global__ __launch_bounds__(256) void k_prep(const float* __restrict__ W0,
                                              const float* __restrict__ W1,
                                              const float* __restrict__ O,
                                              char* __restrict__ ws)
{
    const int unit = blockIdx.x * 4 + (threadIdx.x >> 6);
    const int l = threadIdx.x & 63;
    if (unit < 1280) {
        const float* src; size_t dstoff; int stride;
        if (unit < 1024) {
            int half = unit >> 9, s = (unit >> 4) & 31, nt = unit & 15;
            int k = s*16 + (l >> 5)*8;
            int n = nt*32 + (l & 31);
            src = W0 + (size_t)(half*512 + k) * H0_ + n;
            stride = H0_;
            dstoff = W0FRAG_OFF + (((size_t)(half*32 + s)*16 + nt)*64 + l)*16;
        } else {
            int r = unit - 1024; int s = r >> 3, ct = r & 7;
            int k = s*16 + (l >> 5)*8;
            int n = ct*32 + (l & 31);
            src = W1 + (size_t)k * H1_ + n;
            stride = H1_;
            dstoff = W1FRAG_OFF + (((size_t)(s*8 + ct))*64 + l)*16;
        }
        float f[8];
        #pragma unroll
        for (int j = 0; j < 8; ++j) f[j] = src[(size_t)j * stride];
        u32x4 o = { pk_bf16(f[0],f[1]), pk_bf16(f[2],f[3]), pk_bf16(f[4],f[5]), pk_bf16(f[6],f[7]) };
        *(u32x4*)(ws + dstoff) = o;
    } else {
        const int u = unit - 1280;
        const int s = u / 176, mt = u % 176;
        const int row = mt*32 + (l & 31);
        const int b  = row / (TM1*K_);
        const int rem = row % (TM1*K_);
        const int t  = rem / K_;
        const int i  = rem % K_;
        const float* src = O + (((size_t)(b*T_ + t + 1)*K_ + i)*DIM_) + s*16 + (l >> 5)*8;
        float4 a = *(const float4*)src;
        float4 c = *(const float4*)(src + 4);
        u32x4 o = { pk_bf16(a.x,a.y), pk_bf16(a.z,a.w), pk_bf16(c.x,c.y), pk_bf16(c.z,c.w) };
        *(u32x4*)(ws + OFRAG_OFF + ((size_t)(s*176 + mt)*64 + l)*16) = o;
    }
}

// ---------------------------------------------------------------------------
// k_uv (unchanged — helpers total only ~4.3 µs)
// ---------------------------------------------------------------------------
__global__ __launch_bounds__(256) void k_uv(char* __restrict__ ws,
                                            const float* __restrict__ b0)
{
    const int mb = blockIdx.x;
    const int t  = threadIdx.x, l = t & 63;
    const int nb = blockIdx.y * 4 + (t >> 6);
    const int half = nb >> 3;
    const char* Ag = ws + OFRAG_OFF + ((size_t)(mb*2)*64 + l)*16;
    const char* Bg = ws + W0FRAG_OFF + (size_t)half*524288 + ((size_t)((nb&7)*2)*64 + l)*16;
    const size_t AS = 176*1024, BS = 16*1024;

    f32x16 acc[2][2];
    #pragma unroll
    for (int p = 0; p < 2; ++p)
        #pragma unroll
        for (int c = 0; c < 2; ++c)
            #pragma unroll
            for (int r = 0; r < 16; ++r) acc[p][c][r] = 0.f;

    u32x4 aA[2], bA[2], aB[2], bB[2];
    #pragma unroll
    for (int p = 0; p < 2; ++p) {
        aA[p] = *(const u32x4*)(Ag + 0*AS + p*1024);
        bA[p] = *(const u32x4*)(Bg + 0*BS + p*1024);
        aB[p] = *(const u32x4*)(Ag + 1*AS + p*1024);
        bB[p] = *(const u32x4*)(Bg + 1*BS + p*1024);
    }

    for (int ss = 0; ss < 32; ss += 2) {
        {
            union { u32x4 u[2]; bf16x8 b[2]; } af, bf;
            af.u[0]=aA[0]; af.u[1]=aA[1]; bf.u[0]=bA[0]; bf.u[1]=bA[1];
            if (ss + 2 < 32) {
                #pragma unroll
                for (int p = 0; p < 2; ++p) {
                    aA[p] = *(const u32x4*)(Ag + (size_t)(ss+2)*AS + p*1024);
                    bA[p] = *(const u32x4*)(Bg + (size_t)(ss+2)*BS + p*1024);
                }
            }
            acc[0][0] = __builtin_amdgcn_mfma_f32_32x32x16_bf16(af.b[0], bf.b[0], acc[0][0], 0,0,0);
            acc[0][1] = __builtin_amdgcn_mfma_f32_32x32x16_bf16(af.b[0], bf.b[1], acc[0][1], 0,0,0);
            acc[1][0] = __builtin_amdgcn_mfma_f32_32x32x16_bf16(af.b[1], bf.b[0], acc[1][0], 0,0,0);
            acc[1][1] = __builtin_amdgcn_mfma_f32_32x32x16_bf16(af.b[1], bf.b[1], acc[1][1], 0,0,0);
        }
        {
            union { u32x4 u[2]; bf16x8 b[2]; } af, bf;
            af.u[0]=aB[0]; af.u[1]=aB[1]; bf.u[0]=bB[0]; bf.u[1]=bB[1];
            if (ss + 3 < 32) {
                #pragma unroll
                for (int p = 0; p < 2; ++p) {
                    aB[p] = *(const u32x4*)(Ag + (size_t)(ss+3)*AS + p*1024);
                    bB[p] = *(const u32x4*)(Bg + (size_t)(ss+3)*BS + p*1024);
                }
            }
            acc[0][0] = __builtin_amdgcn_mfma_f32_32x32x16_bf16(af.b[0], bf.b[0], acc[0][0], 0,0,0);
            acc[0][1] = __builtin_amdgcn_mfma_f32_32x32x16_bf16(af.b[0], bf.b[1], acc[0][1], 0,0,0);
            acc[1][0] = __builtin_amdgcn_mfma_f32_32x32x16_bf16(af.b[1], bf.b[0], acc[1][0], 0,0,0);
            acc[1][1] = __builtin_amdgcn_mfma_f32_32x32x16_bf16(af.b[1], bf.b[1], acc[1][1], 0,0,0);
        }
    }

    #pragma unroll
    for (int p = 0; p < 2; ++p) {
        #pragma unroll
        for (int c = 0; c < 2; ++c) {
            const int col = (nb & 7)*64 + c*32 + (l & 31);
            const float bias = (half == 0) ? b0[col] : 0.f;
            #pragma unroll
            for (int r = 0; r < 16; ++r) {
                const int row = (r & 3) + 8*(r >> 2) + 4*(l >> 5);
                const int M = mb*64 + p*32 + row;
                const float v = acc[p][c][r] + bias;
                if (half == 0) {
                    *(unsigned short*)(ws + UB_OFF + ((size_t)M*512 + col)*2) = f2bf(v);
                } else {
                    const int bt = M >> 4, j = M & 15;
                    const int cc = col >> 3;
                    const int c2 = ((cc ^ (j & 7)) << 3) | (col & 7);
                    *(unsigned short*)(ws + VSW_OFF + ((size_t)(bt*16 + j)*512 + c2)*2) = f2bf(v);
                }
            }
        }
    }
}

// ---------------------------------------------------------------------------
// k_obj (unchanged)
// ---------------------------------------------------------------------------
__global__ __launch_bounds__(256) void k_obj(const float* __restrict__ O,
                                             float* __restrict__ out)
{
    __shared__ float red[16][16];
    __shared__ float fl[16];
    const int bt = blockIdx.x;
    const int b_ = bt / TM1, tt = bt % TM1;
    const int t  = threadIdx.x;
    const int i  = t >> 4, s = t & 15;
    const float* base = O + (((size_t)(b_ * T_ + tt + 1) * K_ + i) * DIM_) + s * 32;
    float sum = 0.f;
    #pragma unroll
    for (int q = 0; q < 8; ++q) {
        float4 v = *(const float4*)(base + q * 4);
        sum += v.x + v.y + v.z + v.w;
    }
    red[i][s] = sum;
    __syncthreads();
    if (t < 16) {
        float f = 0.f;
        #pragma unroll
        for (int s2 = 0; s2 < 16; ++s2) f += red[t][s2];
        fl[t] = fminf(fmaxf(f, 0.f), 1.f);
    }
    __syncthreads();
    const float val = fminf((float)(tt + 1) * fl[t >> 4] * fl[t & 15], 1.f);
    __builtin_nontemporal_store(val, out + (size_t)E_ELEMS + (size_t)bt * 256 + t);
}

// ---------------------------------------------------------------------------
// k_e: loop byte-identical to R5/R7 (known-pass); NEW epilogue — LDS-transpose
// to fully-coalesced float4 nt stores (1 KB per wave store instruction).
// ---------------------------------------------------------------------------
#define EBODY(S, WUSE, WLD, DOLOAD)                                            \
    do {                                                                       \
        if (DOLOAD) {                                                          \
            _Pragma("unroll")                                                  \
            for (int c_ = 0; c_ < 4; ++c_)                                     \
                WLD[c_] = *(const u32x4*)(Wg + (size_t)((S)+2)*8192 + c_*1024);\
        }                                                                      \
        const int vchunk_ = ((S)*2 + kc) ^ (jj & 7);                           \
        u32x4 vu_ = *(const u32x4*)(Vs + jj*1024 + vchunk_*16);                \
        float vf_[8];                                                          \
        _Pragma("unroll")                                                      \
        for (int q_ = 0; q_ < 4; ++q_) {                                       \
            vf_[2*q_] = bfu_lo(vu_[q_]); vf_[2*q_+1] = bfu_hi(vu_[q_]);        \
        }                                                                      \
        bf16x8 afrag_[2];                                                      \
        _Pragma("unroll")                                                      \
        for (int p_ = 0; p_ < 2; ++p_) {                                       \
            const int iloc_ = wp*4 + p_*2 + ih;                                \
            u32x4 uu_ = *(const u32x4*)(Us + iloc_*1024 + (S)*32 + kc*16);     \
            u32x4 o_;                                                          \
            _Pragma("unroll")                                                  \
            for (int q_ = 0; q_ < 4; ++q_) {                                   \
                float h0_ = fmaxf(bfu_lo(uu_[q_]) + vf_[2*q_],   0.f);         \
                float h1_ = fmaxf(bfu_hi(uu_[q_]) + vf_[2*q_+1], 0.f);         \
                o_[q_] = cvt_pk(h0_, h1_);                                     \
            }                                                                  \
            union { u32x4 u; bf16x8 b; } cv_; cv_.u = o_; afrag_[p_] = cv_.b;  \
        }                                                                      \
        union { u32x4 u[4]; bf16x8 b[4]; } wcu_;                               \
        _Pragma("unroll")                                                      \
        for (int c_ = 0; c_ < 4; ++c_) wcu_.u[c_] = WUSE[c_];                  \
        _Pragma("unroll")                                                      \
        for (int p_ = 0; p_ < 2; ++p_)                                         \
            _Pragma("unroll")                                                  \
            for (int c_ = 0; c_ < 4; ++c_)                                     \
                acc[p_][c_] = __builtin_amdgcn_mfma_f32_32x32x16_bf16(         \
                    afrag_[p_], wcu_.b[c_], acc[p_][c_], 0, 0, 0);             \
    } while (0)

__global__ __launch_bounds__(256, 2) void k_e(const char* __restrict__ ws,
                                              const float* __restrict__ b1,
                                              float* __restrict__ out)
{
    __shared__ alignas(16) char lds[24576];
    char* Us = lds;
    char* Vs = lds + 8192;

    const int bid = blockIdx.x;
    const int bt = bid >> 1, ph = bid & 1;
    const int t = threadIdx.x, l = t & 63, w = t >> 6;
    const int wp = w & 1, wc = w >> 1;

    const char* Ug = ws + UB_OFF  + (size_t)(bt*16 + ph*8) * 1024;
    const char* Vg = ws + VSW_OFF + (size_t)bt * 16384;
    const char* Wg = ws + W1FRAG_OFF + (size_t)(wc*4)*1024 + (size_t)l*16;

    #pragma unroll
    for (int r = 0; r < 2; ++r) { int c = t + r*256; *(u32x4*)(Us + c*16) = *(const u32x4*)(Ug + c*16); }
    #pragma unroll
    for (int r = 0; r < 4; ++r) { int c = t + r*256; *(u32x4*)(Vs + c*16) = *(const u32x4*)(Vg + c*16); }
    __syncthreads();

    f32x16 acc[2][4];
    #pragma unroll
    for (int p = 0; p < 2; ++p)
        #pragma unroll
        for (int c = 0; c < 4; ++c)
            #pragma unroll
            for (int r = 0; r < 16; ++r) acc[p][c][r] = 0.f;

    const int jj = l & 15;
    const int kc = l >> 5;
    const int ih = (l >> 4) & 1;

    u32x4 wk0[4], wk1[4], wk2[4], wk3[4];
    #pragma unroll
    for (int c = 0; c < 4; ++c) wk0[c] = *(const u32x4*)(Wg + c*1024);
    #pragma unroll
    for (int c = 0; c < 4; ++c) wk1[c] = *(const u32x4*)(Wg + 8192 + c*1024);

    for (int j = 0; j < 8; ++j) {
        const int s = j * 4;
        EBODY(s+0, wk0, wk2, true);
        EBODY(s+1, wk1, wk3, true);
        EBODY(s+2, wk2, wk0, (j < 7));
        EBODY(s+3, wk3, wk1, (j < 7));
    }

    // ---- coalesced epilogue: transpose each 128x32 slice via LDS ----
    __syncthreads();                          // everyone done reading Us/Vs
    float* tb = (float*)lds;                  // [128][36] f32 = 18,432 B
    const int rbase = wp*64 + 4*(l >> 5);     // + p*32 + (r&3) + 8*(r>>2)
    const int wcol  = l & 31;
    #pragma unroll
    for (int sl = 0; sl < 8; ++sl) {
        const int wcs = sl >> 2, cs = sl & 3;
        if (wc == wcs) {
            #pragma unroll
            for (int p = 0; p < 2; ++p)
                #pragma unroll
                for (int r = 0; r < 16; ++r)
                    tb[(rbase + p*32 + (r & 3) + 8*(r >> 2))*36 + wcol] = acc[p][cs][r];
        }
        __syncthreads();
        const int colbase = wcs*128 + cs*32;
        const int row0 = t >> 3, c40 = (t & 7) * 4;
        const float4 bbv = *(const float4*)&b1[colbase + c40];
        #pragma unroll
        for (int q = 0; q < 4; ++q) {
            const int row = q*32 + row0;
            float4 v = *(const float4*)&tb[row*36 + c40];
            f32x4 o = { fmaxf(v.x + bbv.x, 0.f), fmaxf(v.y + bbv.y, 0.f),
                        fmaxf(v.z + bbv.z, 0.f), fmaxf(v.w + bbv.w, 0.f) };
            __builtin_nontemporal_store(o,
                (f32x4*)(out + ((size_t)bt*256 + ph*128 + row)*256 + colbase + c40));
        }
        __syncthreads();
    }
}

// ---------------------------------------------------------------------------
extern "C" void kernel_launch(void* const* d_in, const int* in_sizes, int n_in,
                              void* d_out, int out_size, void* d_ws, size_t ws_size,
                              hipStream_t stream) {
    const float* O  = (const float*)d_in[0];
    const float* W0 = (const float*)d_in[1];
    const float* b0 = (const float*)d_in[2];
    const float* W1 = (const float*)d_in[3];
    const float* b1 = (const float*)d_in[4];
    float* out = (float*)d_out;
    char* ws = (char*)d_ws;

    k_prep<<<1728, 256, 0, stream>>>(W0, W1, O, ws);
    dim3 guv(88, 4);
    k_uv<<<guv, 256, 0, stream>>>(ws, b0);
    k_obj<<<NBT, 256, 0, stream>>>(O, out);
    k_e<<<NBT * 2, 256, 0, stream>>>(ws, b1, out);
}

// Round 10
// 70.100 us; speedup vs baseline: 2.0120x; 1.0113x over previous
//
#include <hip/hip_runtime.h>
#include <hip/hip_bf16.h>

#define B_    32
#define T_    12
#define TM1   11
#define K_    16
#define DIM_  512
#define H0_   512
#define H1_   256
#define NROWS 5632
#define NBT   352
#define E_ELEMS (NBT*256*H1_)

typedef __bf16 bf16x8 __attribute__((ext_vector_type(8)));
typedef float  f32x16 __attribute__((ext_vector_type(16)));
typedef float  f32x4  __attribute__((ext_vector_type(4)));
typedef unsigned u32x4 __attribute__((ext_vector_type(4)));

#define OFRAG_OFF   0
#define W0FRAG_OFF  5767168
#define W1FRAG_OFF  (W0FRAG_OFF + 1048576)
#define UB_OFF      (W1FRAG_OFF + 262144)
#define VSW_OFF     (UB_OFF + 5767168)

__device__ __forceinline__ unsigned bf_rn(float f) {
    unsigned u = __float_as_uint(f);
    return (u + 0x7fffu + ((u >> 16) & 1u)) >> 16;
}
__device__ __forceinline__ unsigned pk_bf16(float lo, float hi) {
    return bf_rn(lo) | (bf_rn(hi) << 16);
}
__device__ __forceinline__ unsigned short f2bf(float f) {
    return (unsigned short)bf_rn(f);
}
__device__ __forceinline__ float bfu_lo(unsigned u) { return __uint_as_float(u << 16); }
__device__ __forceinline__ float bfu_hi(unsigned u) { return __uint_as_float(u & 0xffff0000u); }
__device__ __forceinline__ unsigned cvt_pk(float lo, float hi) {
    unsigned r;
    asm("v_cvt_pk_bf16_f32 %0, %1, %2" : "=v"(r) : "v"(lo), "v"(hi));
    return r;
}

// ---------------------------------------------------------------------------
// k_prep: merged W0/W1/O fragment repack (bf16, fragment-ordered).
// ---------------------------------------------------------------------------
__global__ __launch_bounds__(256) void k_prep(const float* __restrict__ W0,
                                              const float* __restrict__ W1,
                                              const float* __restrict__ O,
                                              char* __restrict__ ws)
{
    const int unit = blockIdx.x * 4 + (threadIdx.x >> 6);
    const int l = threadIdx.x & 63;
    if (unit < 1280) {
        const float* src; size_t dstoff; int stride;
        if (unit < 1024) {
            int half = unit >> 9, s = (unit >> 4) & 31, nt = unit & 15;
            int k = s*16 + (l >> 5)*8;
            int n = nt*32 + (l & 31);
            src = W0 + (size_t)(half*512 + k) * H0_ + n;
            stride = H0_;
            dstoff = W0FRAG_OFF + (((size_t)(half*32 + s)*16 + nt)*64 + l)*16;
        } else {
            int r = unit - 1024; int s = r >> 3, ct = r & 7;
            int k = s*16 + (l >> 5)*8;
            int n = ct*32 + (l & 31);
            src = W1 + (size_t)k * H1_ + n;
            stride = H1_;
            dstoff = W1FRAG_OFF + (((size_t)(s*8 + ct))*64 + l)*16;
        }
        float f[8];
        #pragma unroll
        for (int j = 0; j < 8; ++j) f[j] = src[(size_t)j * stride];
        u32x4 o = { pk_bf16(f[0],f[1]), pk_bf16(f[2],f[3]), pk_bf16(f[4],f[5]), pk_bf16(f[6],f[7]) };
        *(u32x4*)(ws + dstoff) = o;
    } else {
        const int u = unit - 1280;
        const int s = u / 176, mt = u % 176;
        const int row = mt*32 + (l & 31);
        const int b  = row / (TM1*K_);
        const int rem = row % (TM1*K_);
        const int t  = rem / K_;
        const int i  = rem % K_;
        const float* src = O + (((size_t)(b*T_ + t + 1)*K_ + i)*DIM_) + s*16 + (l >> 5)*8;
        float4 a = *(const float4*)src;
        float4 c = *(const float4*)(src + 4);
        u32x4 o = { pk_bf16(a.x,a.y), pk_bf16(a.z,a.w), pk_bf16(c.x,c.y), pk_bf16(c.z,c.w) };
        *(u32x4*)(ws + OFRAG_OFF + ((size_t)(s*176 + mt)*64 + l)*16) = o;
    }
}

// ---------------------------------------------------------------------------
// k_uv (unchanged)
// ---------------------------------------------------------------------------
__global__ __launch_bounds__(256) void k_uv(char* __restrict__ ws,
                                            const float* __restrict__ b0)
{
    const int mb = blockIdx.x;
    const int t  = threadIdx.x, l = t & 63;
    const int nb = blockIdx.y * 4 + (t >> 6);
    const int half = nb >> 3;
    const char* Ag = ws + OFRAG_OFF + ((size_t)(mb*2)*64 + l)*16;
    const char* Bg = ws + W0FRAG_OFF + (size_t)half*524288 + ((size_t)((nb&7)*2)*64 + l)*16;
    const size_t AS = 176*1024, BS = 16*1024;

    f32x16 acc[2][2];
    #pragma unroll
    for (int p = 0; p < 2; ++p)
        #pragma unroll
        for (int c = 0; c < 2; ++c)
            #pragma unroll
            for (int r = 0; r < 16; ++r) acc[p][c][r] = 0.f;

    u32x4 aA[2], bA[2], aB[2], bB[2];
    #pragma unroll
    for (int p = 0; p < 2; ++p) {
        aA[p] = *(const u32x4*)(Ag + 0*AS + p*1024);
        bA[p] = *(const u32x4*)(Bg + 0*BS + p*1024);
        aB[p] = *(const u32x4*)(Ag + 1*AS + p*1024);
        bB[p] = *(const u32x4*)(Bg + 1*BS + p*1024);
    }

    for (int ss = 0; ss < 32; ss += 2) {
        {
            union { u32x4 u[2]; bf16x8 b[2]; } af, bf;
            af.u[0]=aA[0]; af.u[1]=aA[1]; bf.u[0]=bA[0]; bf.u[1]=bA[1];
            if (ss + 2 < 32) {
                #pragma unroll
                for (int p = 0; p < 2; ++p) {
                    aA[p] = *(const u32x4*)(Ag + (size_t)(ss+2)*AS + p*1024);
                    bA[p] = *(const u32x4*)(Bg + (size_t)(ss+2)*BS + p*1024);
                }
            }
            acc[0][0] = __builtin_amdgcn_mfma_f32_32x32x16_bf16(af.b[0], bf.b[0], acc[0][0], 0,0,0);
            acc[0][1] = __builtin_amdgcn_mfma_f32_32x32x16_bf16(af.b[0], bf.b[1], acc[0][1], 0,0,0);
            acc[1][0] = __builtin_amdgcn_mfma_f32_32x32x16_bf16(af.b[1], bf.b[0], acc[1][0], 0,0,0);
            acc[1][1] = __builtin_amdgcn_mfma_f32_32x32x16_bf16(af.b[1], bf.b[1], acc[1][1], 0,0,0);
        }
        {
            union { u32x4 u[2]; bf16x8 b[2]; } af, bf;
            af.u[0]=aB[0]; af.u[1]=aB[1]; bf.u[0]=bB[0]; bf.u[1]=bB[1];
            if (ss + 3 < 32) {
                #pragma unroll
                for (int p = 0; p < 2; ++p) {
                    aB[p] = *(const u32x4*)(Ag + (size_t)(ss+3)*AS + p*1024);
                    bB[p] = *(const u32x4*)(Bg + (size_t)(ss+3)*BS + p*1024);
                }
            }
            acc[0][0] = __builtin_amdgcn_mfma_f32_32x32x16_bf16(af.b[0], bf.b[0], acc[0][0], 0,0,0);
            acc[0][1] = __builtin_amdgcn_mfma_f32_32x32x16_bf16(af.b[0], bf.b[1], acc[0][1], 0,0,0);
            acc[1][0] = __builtin_amdgcn_mfma_f32_32x32x16_bf16(af.b[1], bf.b[0], acc[1][0], 0,0,0);
            acc[1][1] = __builtin_amdgcn_mfma_f32_32x32x16_bf16(af.b[1], bf.b[1], acc[1][1], 0,0,0);
        }
    }

    #pragma unroll
    for (int p = 0; p < 2; ++p) {
        #pragma unroll
        for (int c = 0; c < 2; ++c) {
            const int col = (nb & 7)*64 + c*32 + (l & 31);
            const float bias = (half == 0) ? b0[col] : 0.f;
            #pragma unroll
            for (int r = 0; r < 16; ++r) {
                const int row = (r & 3) + 8*(r >> 2) + 4*(l >> 5);
                const int M = mb*64 + p*32 + row;
                const float v = acc[p][c][r] + bias;
                if (half == 0) {
                    *(unsigned short*)(ws + UB_OFF + ((size_t)M*512 + col)*2) = f2bf(v);
                } else {
                    const int bt = M >> 4, j = M & 15;
                    const int cc = col >> 3;
                    const int c2 = ((cc ^ (j & 7)) << 3) | (col & 7);
                    *(unsigned short*)(ws + VSW_OFF + ((size_t)(bt*16 + j)*512 + c2)*2) = f2bf(v);
                }
            }
        }
    }
}

// ---------------------------------------------------------------------------
// k_obj (unchanged)
// ---------------------------------------------------------------------------
__global__ __launch_bounds__(256) void k_obj(const float* __restrict__ O,
                                             float* __restrict__ out)
{
    __shared__ float red[16][16];
    __shared__ float fl[16];
    const int bt = blockIdx.x;
    const int b_ = bt / TM1, tt = bt % TM1;
    const int t  = threadIdx.x;
    const int i  = t >> 4, s = t & 15;
    const float* base = O + (((size_t)(b_ * T_ + tt + 1) * K_ + i) * DIM_) + s * 32;
    float sum = 0.f;
    #pragma unroll
    for (int q = 0; q < 8; ++q) {
        float4 v = *(const float4*)(base + q * 4);
        sum += v.x + v.y + v.z + v.w;
    }
    red[i][s] = sum;
    __syncthreads();
    if (t < 16) {
        float f = 0.f;
        #pragma unroll
        for (int s2 = 0; s2 < 16; ++s2) f += red[t][s2];
        fl[t] = fminf(fmaxf(f, 0.f), 1.f);
    }
    __syncthreads();
    const float val = fminf((float)(tt + 1) * fl[t >> 4] * fl[t & 15], 1.f);
    __builtin_nontemporal_store(val, out + (size_t)E_ELEMS + (size_t)bt * 256 + t);
}

// ---------------------------------------------------------------------------
// k_e v3 (slim): block = 128 pairs x 128 cols, 4 waves, wave = 32 pairs x 128
// cols -> acc = 4 x f32x16 = 64 AGPR. __launch_bounds__(256,3) caps regs at
// 170 total -> 3 waves/SIMD (vs 2). One afrag/step shared by 4 MFMAs; W1 via
// 2-bank register pipeline (32 VGPR). No barriers in loop.
// ---------------------------------------------------------------------------
#define KSTEP(S, WK)                                                           \
    do {                                                                       \
        const int vch_ = (((S)*2 + kc) ^ jlow_);                               \
        u32x4 vu_ = *(const u32x4*)(VsL + vch_*16);                            \
        u32x4 uu_ = *(const u32x4*)(UsL + (S)*32);                             \
        u32x4 o_;                                                              \
        _Pragma("unroll")                                                      \
        for (int q_ = 0; q_ < 4; ++q_) {                                       \
            float h0_ = fmaxf(bfu_lo(uu_[q_]) + bfu_lo(vu_[q_]), 0.f);         \
            float h1_ = fmaxf(bfu_hi(uu_[q_]) + bfu_hi(vu_[q_]), 0.f);         \
            o_[q_] = cvt_pk(h0_, h1_);                                         \
        }                                                                      \
        union { u32x4 u; bf16x8 b; } af_; af_.u = o_;                          \
        union { u32x4 u[4]; bf16x8 b[4]; } wu_;                                \
        _Pragma("unroll")                                                      \
        for (int c_ = 0; c_ < 4; ++c_) wu_.u[c_] = WK[c_];                     \
        acc0 = __builtin_amdgcn_mfma_f32_32x32x16_bf16(af_.b, wu_.b[0], acc0, 0,0,0); \
        acc1 = __builtin_amdgcn_mfma_f32_32x32x16_bf16(af_.b, wu_.b[1], acc1, 0,0,0); \
        acc2 = __builtin_amdgcn_mfma_f32_32x32x16_bf16(af_.b, wu_.b[2], acc2, 0,0,0); \
        acc3 = __builtin_amdgcn_mfma_f32_32x32x16_bf16(af_.b, wu_.b[3], acc3, 0,0,0); \
    } while (0)

__global__ __launch_bounds__(256, 3) void k_e(const char* __restrict__ ws,
                                              const float* __restrict__ b1,
                                              float* __restrict__ out)
{
    __shared__ alignas(16) char lds[24576];
    char* Us = lds;                 // [8][512] bf16 (rows ph*8 .. ph*8+7)
    char* Vs = lds + 8192;          // [16][512] bf16 (chunk-XOR content)

    const int bid = blockIdx.x;     // ((bt*2 + ph)*2 + ch)
    const int ch = bid & 1, ph = (bid >> 1) & 1, bt = bid >> 2;
    const int t = threadIdx.x, l = t & 63, wp = t >> 6;

    const char* Ug = ws + UB_OFF  + (size_t)(bt*16 + ph*8) * 1024;
    const char* Vg = ws + VSW_OFF + (size_t)bt * 16384;
    const char* Wg = ws + W1FRAG_OFF + (size_t)(ch*4)*1024 + (size_t)l*16;

    #pragma unroll
    for (int r = 0; r < 2; ++r) { int c = t + r*256; *(u32x4*)(Us + c*16) = *(const u32x4*)(Ug + c*16); }
    #pragma unroll
    for (int r = 0; r < 4; ++r) { int c = t + r*256; *(u32x4*)(Vs + c*16) = *(const u32x4*)(Vg + c*16); }
    __syncthreads();

    f32x16 acc0, acc1, acc2, acc3;
    #pragma unroll
    for (int r = 0; r < 16; ++r) { acc0[r] = 0.f; acc1[r] = 0.f; acc2[r] = 0.f; acc3[r] = 0.f; }

    const int jj   = l & 15;
    const int jlow_ = jj & 7;
    const int kc   = l >> 5;
    const int il   = wp*2 + ((l >> 4) & 1);       // local Us row
    const char* UsL = Us + il*1024 + kc*16;       // + s*32
    const char* VsL = Vs + jj*1024;               // + vchunk*16

    u32x4 wA[4], wB[4];
    #pragma unroll
    for (int c = 0; c < 4; ++c) wA[c] = *(const u32x4*)(Wg + c*1024);

    for (int sj = 0; sj < 16; ++sj) {
        const int s0 = sj * 2;
        #pragma unroll
        for (int c = 0; c < 4; ++c)
            wB[c] = *(const u32x4*)(Wg + (size_t)(s0+1)*8192 + c*1024);
        KSTEP(s0, wA);
        if (sj < 15) {
            #pragma unroll
            for (int c = 0; c < 4; ++c)
                wA[c] = *(const u32x4*)(Wg + (size_t)(s0+2)*8192 + c*1024);
        }
        KSTEP(s0+1, wB);
    }

    // epilogue: + b1, relu, nt scalar stores (store path exonerated in R9)
    const int colb = ch*128 + (l & 31);
    const int pr0  = ph*128 + wp*32 + 4*(l >> 5);
    float* ob = out + ((size_t)bt*256 + pr0)*256 + colb;
    #define EPI(ACC, CT)                                                       \
        do {                                                                   \
            const float bb_ = b1[colb + (CT)*32];                              \
            _Pragma("unroll")                                                  \
            for (int r_ = 0; r_ < 16; ++r_) {                                  \
                const int rr_ = (r_ & 3) + 8*(r_ >> 2);                        \
                __builtin_nontemporal_store(fmaxf(ACC[r_] + bb_, 0.f),         \
                    ob + (size_t)rr_*256 + (CT)*32);                           \
            }                                                                  \
        } while (0)
    EPI(acc0, 0);
    EPI(acc1, 1);
    EPI(acc2, 2);
    EPI(acc3, 3);
    #undef EPI
}

// ---------------------------------------------------------------------------
extern "C" void kernel_launch(void* const* d_in, const int* in_sizes, int n_in,
                              void* d_out, int out_size, void* d_ws, size_t ws_size,
                              hipStream_t stream) {
    const float* O  = (const float*)d_in[0];
    const float* W0 = (const float*)d_in[1];
    const float* b0 = (const float*)d_in[2];
    const float* W1 = (const float*)d_in[3];
    const float* b1 = (const float*)d_in[4];
    float* out = (float*)d_out;
    char* ws = (char*)d_ws;

    k_prep<<<1728, 256, 0, stream>>>(W0, W1, O, ws);
    dim3 guv(88, 4);
    k_uv<<<guv, 256, 0, stream>>>(ws, b0);
    k_obj<<<NBT, 256, 0, stream>>>(O, out);
    k_e<<<NBT * 4, 256, 0, stream>>>(ws, b1, out);
}

// Round 11
// 65.461 us; speedup vs baseline: 2.1546x; 1.0709x over previous
//
#include <hip/hip_runtime.h>
#include <hip/hip_bf16.h>

#define B_    32
#define T_    12
#define TM1   11
#define K_    16
#define DIM_  512
#define H0_   512
#define H1_   256
#define NROWS 5632
#define NBT   352
#define E_ELEMS (NBT*256*H1_)

typedef __bf16 bf16x8 __attribute__((ext_vector_type(8)));
typedef float  f32x16 __attribute__((ext_vector_type(16)));
typedef float  f32x4  __attribute__((ext_vector_type(4)));
typedef unsigned u32x4 __attribute__((ext_vector_type(4)));

#define OFRAG_OFF   0
#define W0FRAG_OFF  5767168
#define W1FRAG_OFF  (W0FRAG_OFF + 1048576)
#define UB_OFF      (W1FRAG_OFF + 262144)
#define VSW_OFF     (UB_OFF + 5767168)

__device__ __forceinline__ unsigned bf_rn(float f) {
    unsigned u = __float_as_uint(f);
    return (u + 0x7fffu + ((u >> 16) & 1u)) >> 16;
}
__device__ __forceinline__ unsigned pk_bf16(float lo, float hi) {
    return bf_rn(lo) | (bf_rn(hi) << 16);
}
__device__ __forceinline__ unsigned short f2bf(float f) {
    return (unsigned short)bf_rn(f);
}
__device__ __forceinline__ float bfu_lo(unsigned u) { return __uint_as_float(u << 16); }
__device__ __forceinline__ float bfu_hi(unsigned u) { return __uint_as_float(u & 0xffff0000u); }
__device__ __forceinline__ unsigned cvt_pk(float lo, float hi) {
    unsigned r;
    asm("v_cvt_pk_bf16_f32 %0, %1, %2" : "=v"(r) : "v"(lo), "v"(hi));
    return r;
}
// async global->LDS, 16B per lane, no VGPR round-trip
__device__ __forceinline__ void gl2lds16(const char* g, char* l) {
    __builtin_amdgcn_global_load_lds(
        (const __attribute__((address_space(1))) unsigned*)(const void*)g,
        (__attribute__((address_space(3))) unsigned*)(void*)l, 16, 0, 0);
}

// ---------------------------------------------------------------------------
// k_prep: merged W0/W1/O fragment repack (bf16, fragment-ordered).
// ---------------------------------------------------------------------------
__global__ __launch_bounds__(256) void k_prep(const float* __restrict__ W0,
                                              const float* __restrict__ W1,
                                              const float* __restrict__ O,
                                              char* __restrict__ ws)
{
    const int unit = blockIdx.x * 4 + (threadIdx.x >> 6);
    const int l = threadIdx.x & 63;
    if (unit < 1280) {
        const float* src; size_t dstoff; int stride;
        if (unit < 1024) {
            int half = unit >> 9, s = (unit >> 4) & 31, nt = unit & 15;
            int k = s*16 + (l >> 5)*8;
            int n = nt*32 + (l & 31);
            src = W0 + (size_t)(half*512 + k) * H0_ + n;
            stride = H0_;
            dstoff = W0FRAG_OFF + (((size_t)(half*32 + s)*16 + nt)*64 + l)*16;
        } else {
            int r = unit - 1024; int s = r >> 3, ct = r & 7;
            int k = s*16 + (l >> 5)*8;
            int n = ct*32 + (l & 31);
            src = W1 + (size_t)k * H1_ + n;
            stride = H1_;
            dstoff = W1FRAG_OFF + (((size_t)(s*8 + ct))*64 + l)*16;
        }
        float f[8];
        #pragma unroll
        for (int j = 0; j < 8; ++j) f[j] = src[(size_t)j * stride];
        u32x4 o = { pk_bf16(f[0],f[1]), pk_bf16(f[2],f[3]), pk_bf16(f[4],f[5]), pk_bf16(f[6],f[7]) };
        *(u32x4*)(ws + dstoff) = o;
    } else {
        const int u = unit - 1280;
        const int s = u / 176, mt = u % 176;
        const int row = mt*32 + (l & 31);
        const int b  = row / (TM1*K_);
        const int rem = row % (TM1*K_);
        const int t  = rem / K_;
        const int i  = rem % K_;
        const float* src = O + (((size_t)(b*T_ + t + 1)*K_ + i)*DIM_) + s*16 + (l >> 5)*8;
        float4 a = *(const float4*)src;
        float4 c = *(const float4*)(src + 4);
        u32x4 o = { pk_bf16(a.x,a.y), pk_bf16(a.z,a.w), pk_bf16(c.x,c.y), pk_bf16(c.z,c.w) };
        *(u32x4*)(ws + OFRAG_OFF + ((size_t)(s*176 + mt)*64 + l)*16) = o;
    }
}

// ---------------------------------------------------------------------------
// k_uv (unchanged)
// ---------------------------------------------------------------------------
__global__ __launch_bounds__(256) void k_uv(char* __restrict__ ws,
                                            const float* __restrict__ b0)
{
    const int mb = blockIdx.x;
    const int t  = threadIdx.x, l = t & 63;
    const int nb = blockIdx.y * 4 + (t >> 6);
    const int half = nb >> 3;
    const char* Ag = ws + OFRAG_OFF + ((size_t)(mb*2)*64 + l)*16;
    const char* Bg = ws + W0FRAG_OFF + (size_t)half*524288 + ((size_t)((nb&7)*2)*64 + l)*16;
    const size_t AS = 176*1024, BS = 16*1024;

    f32x16 acc[2][2];
    #pragma unroll
    for (int p = 0; p < 2; ++p)
        #pragma unroll
        for (int c = 0; c < 2; ++c)
            #pragma unroll
            for (int r = 0; r < 16; ++r) acc[p][c][r] = 0.f;

    u32x4 aA[2], bA[2], aB[2], bB[2];
    #pragma unroll
    for (int p = 0; p < 2; ++p) {
        aA[p] = *(const u32x4*)(Ag + 0*AS + p*1024);
        bA[p] = *(const u32x4*)(Bg + 0*BS + p*1024);
        aB[p] = *(const u32x4*)(Ag + 1*AS + p*1024);
        bB[p] = *(const u32x4*)(Bg + 1*BS + p*1024);
    }

    for (int ss = 0; ss < 32; ss += 2) {
        {
            union { u32x4 u[2]; bf16x8 b[2]; } af, bf;
            af.u[0]=aA[0]; af.u[1]=aA[1]; bf.u[0]=bA[0]; bf.u[1]=bA[1];
            if (ss + 2 < 32) {
                #pragma unroll
                for (int p = 0; p < 2; ++p) {
                    aA[p] = *(const u32x4*)(Ag + (size_t)(ss+2)*AS + p*1024);
                    bA[p] = *(const u32x4*)(Bg + (size_t)(ss+2)*BS + p*1024);
                }
            }
            acc[0][0] = __builtin_amdgcn_mfma_f32_32x32x16_bf16(af.b[0], bf.b[0], acc[0][0], 0,0,0);
            acc[0][1] = __builtin_amdgcn_mfma_f32_32x32x16_bf16(af.b[0], bf.b[1], acc[0][1], 0,0,0);
            acc[1][0] = __builtin_amdgcn_mfma_f32_32x32x16_bf16(af.b[1], bf.b[0], acc[1][0], 0,0,0);
            acc[1][1] = __builtin_amdgcn_mfma_f32_32x32x16_bf16(af.b[1], bf.b[1], acc[1][1], 0,0,0);
        }
        {
            union { u32x4 u[2]; bf16x8 b[2]; } af, bf;
            af.u[0]=aB[0]; af.u[1]=aB[1]; bf.u[0]=bB[0]; bf.u[1]=bB[1];
            if (ss + 3 < 32) {
                #pragma unroll
                for (int p = 0; p < 2; ++p) {
                    aB[p] = *(const u32x4*)(Ag + (size_t)(ss+3)*AS + p*1024);
                    bB[p] = *(const u32x4*)(Bg + (size_t)(ss+3)*BS + p*1024);
                }
            }
            acc[0][0] = __builtin_amdgcn_mfma_f32_32x32x16_bf16(af.b[0], bf.b[0], acc[0][0], 0,0,0);
            acc[0][1] = __builtin_amdgcn_mfma_f32_32x32x16_bf16(af.b[0], bf.b[1], acc[0][1], 0,0,0);
            acc[1][0] = __builtin_amdgcn_mfma_f32_32x32x16_bf16(af.b[1], bf.b[0], acc[1][0], 0,0,0);
            acc[1][1] = __builtin_amdgcn_mfma_f32_32x32x16_bf16(af.b[1], bf.b[1], acc[1][1], 0,0,0);
        }
    }

    #pragma unroll
    for (int p = 0; p < 2; ++p) {
        #pragma unroll
        for (int c = 0; c < 2; ++c) {
            const int col = (nb & 7)*64 + c*32 + (l & 31);
            const float bias = (half == 0) ? b0[col] : 0.f;
            #pragma unroll
            for (int r = 0; r < 16; ++r) {
                const int row = (r & 3) + 8*(r >> 2) + 4*(l >> 5);
                const int M = mb*64 + p*32 + row;
                const float v = acc[p][c][r] + bias;
                if (half == 0) {
                    *(unsigned short*)(ws + UB_OFF + ((size_t)M*512 + col)*2) = f2bf(v);
                } else {
                    const int bt = M >> 4, j = M & 15;
                    const int cc = col >> 3;
                    const int c2 = ((cc ^ (j & 7)) << 3) | (col & 7);
                    *(unsigned short*)(ws + VSW_OFF + ((size_t)(bt*16 + j)*512 + c2)*2) = f2bf(v);
                }
            }
        }
    }
}

// ---------------------------------------------------------------------------
// k_obj (unchanged)
// ---------------------------------------------------------------------------
__global__ __launch_bounds__(256) void k_obj(const float* __restrict__ O,
                                             float* __restrict__ out)
{
    __shared__ float red[16][16];
    __shared__ float fl[16];
    const int bt = blockIdx.x;
    const int b_ = bt / TM1, tt = bt % TM1;
    const int t  = threadIdx.x;
    const int i  = t >> 4, s = t & 15;
    const float* base = O + (((size_t)(b_ * T_ + tt + 1) * K_ + i) * DIM_) + s * 32;
    float sum = 0.f;
    #pragma unroll
    for (int q = 0; q < 8; ++q) {
        float4 v = *(const float4*)(base + q * 4);
        sum += v.x + v.y + v.z + v.w;
    }
    red[i][s] = sum;
    __syncthreads();
    if (t < 16) {
        float f = 0.f;
        #pragma unroll
        for (int s2 = 0; s2 < 16; ++s2) f += red[t][s2];
        fl[t] = fminf(fmaxf(f, 0.f), 1.f);
    }
    __syncthreads();
    const float val = fminf((float)(tt + 1) * fl[t >> 4] * fl[t & 15], 1.f);
    __builtin_nontemporal_store(val, out + (size_t)E_ELEMS + (size_t)bt * 256 + t);
}

// ---------------------------------------------------------------------------
// k_e v4: W1 staged to LDS via global_load_lds, double-buffered 8KB chunks
// (2 K-steps each). Loads issued BEFORE chunk compute -> barrier drain hits
// loads ~500cy after issue (no reg round-trip). 4 waves share each staged
// chunk (4x less L2 traffic than v3). LDS 40KB: Us 8K + Vs 16K + Wbuf 16K.
// Block = 128 pairs x 128 cols (bt, ph, ch); wave = 32 pairs x 128 cols.
// ---------------------------------------------------------------------------
#define WSTAGE(C, BUFOFF)                                                      \
    do {                                                                       \
        gl2lds16(Wsrc + (size_t)((C)*2 + 0)*8192, Wbuf + (BUFOFF) + wq*1024);  \
        gl2lds16(Wsrc + (size_t)((C)*2 + 1)*8192, Wbuf + (BUFOFF) + 4096 + wq*1024); \
    } while (0)

#define KSTEP_L(S, BUFOFF, ST)                                                 \
    do {                                                                       \
        const int vch_ = (((S)*2 + kc) ^ jlow_);                               \
        u32x4 vu_ = *(const u32x4*)(VsL + vch_*16);                            \
        u32x4 uu_ = *(const u32x4*)(UsL + (S)*32);                             \
        u32x4 o_;                                                              \
        _Pragma("unroll")                                                      \
        for (int q_ = 0; q_ < 4; ++q_) {                                       \
            float h0_ = fmaxf(bfu_lo(uu_[q_]) + bfu_lo(vu_[q_]), 0.f);         \
            float h1_ = fmaxf(bfu_hi(uu_[q_]) + bfu_hi(vu_[q_]), 0.f);         \
            o_[q_] = cvt_pk(h0_, h1_);                                         \
        }                                                                      \
        union { u32x4 u; bf16x8 b; } af_; af_.u = o_;                          \
        union { u32x4 u[4]; bf16x8 b[4]; } wu_;                                \
        _Pragma("unroll")                                                      \
        for (int c_ = 0; c_ < 4; ++c_)                                         \
            wu_.u[c_] = *(const u32x4*)(WlL + (BUFOFF) + (ST)*4096 + c_*1024); \
        acc0 = __builtin_amdgcn_mfma_f32_32x32x16_bf16(af_.b, wu_.b[0], acc0, 0,0,0); \
        acc1 = __builtin_amdgcn_mfma_f32_32x32x16_bf16(af_.b, wu_.b[1], acc1, 0,0,0); \
        acc2 = __builtin_amdgcn_mfma_f32_32x32x16_bf16(af_.b, wu_.b[2], acc2, 0,0,0); \
        acc3 = __builtin_amdgcn_mfma_f32_32x32x16_bf16(af_.b, wu_.b[3], acc3, 0,0,0); \
    } while (0)

__global__ __launch_bounds__(256, 3) void k_e(const char* __restrict__ ws,
                                              const float* __restrict__ b1,
                                              float* __restrict__ out)
{
    __shared__ alignas(16) char lds[40960];
    char* Us   = lds;                 // [8][512] bf16
    char* Vs   = lds + 8192;          // [16][512] bf16 (chunk-XOR content)
    char* Wbuf = lds + 24576;         // 2 x 8KB W1 chunk double-buffer

    const int bid = blockIdx.x;       // ((bt*2 + ph)*2 + ch)
    const int ch = bid & 1, ph = (bid >> 1) & 1, bt = bid >> 2;
    const int t = threadIdx.x, l = t & 63, wq = t >> 6;

    const char* Ug = ws + UB_OFF  + (size_t)(bt*16 + ph*8) * 1024;
    const char* Vg = ws + VSW_OFF + (size_t)bt * 16384;
    // per-lane source base: step-stride 8192; within step: ch*4096 + seg(wq)*1024 + l*16
    const char* Wsrc = ws + W1FRAG_OFF + (size_t)ch*4096 + (size_t)wq*1024 + (size_t)l*16;

    #pragma unroll
    for (int r = 0; r < 2; ++r) { int c = t + r*256; *(u32x4*)(Us + c*16) = *(const u32x4*)(Ug + c*16); }
    #pragma unroll
    for (int r = 0; r < 4; ++r) { int c = t + r*256; *(u32x4*)(Vs + c*16) = *(const u32x4*)(Vg + c*16); }

    // prologue: stage chunk 0 into buf0 (drained by the syncthreads below)
    WSTAGE(0, 0);
    __syncthreads();

    f32x16 acc0, acc1, acc2, acc3;
    #pragma unroll
    for (int r = 0; r < 16; ++r) { acc0[r] = 0.f; acc1[r] = 0.f; acc2[r] = 0.f; acc3[r] = 0.f; }

    const int jj    = l & 15;
    const int jlow_ = jj & 7;
    const int kc    = l >> 5;
    const int il    = wq*2 + ((l >> 4) & 1);
    const char* UsL = Us + il*1024 + kc*16;
    const char* VsL = Vs + jj*1024;
    const char* WlL = Wbuf + (size_t)l*16;

    for (int j = 0; j < 8; ++j) {
        const int c0 = j*2;                // chunk index in buf0
        // phase A: compute chunk c0 from buf0, prefetch chunk c0+1 -> buf1
        if (c0 + 1 < 16) WSTAGE(c0+1, 8192);
        KSTEP_L(c0*2+0, 0, 0);
        KSTEP_L(c0*2+1, 0, 1);
        __syncthreads();                   // drains buf1 loads (in flight during compute)
        // phase B: compute chunk c0+1 from buf1, prefetch chunk c0+2 -> buf0
        if (c0 + 2 < 16) WSTAGE(c0+2, 0);
        KSTEP_L(c0*2+2, 8192, 0);
        KSTEP_L(c0*2+3, 8192, 1);
        __syncthreads();
    }

    // epilogue: + b1, relu, nt scalar stores (store path exonerated in R9)
    const int colb = ch*128 + (l & 31);
    const int pr0  = ph*128 + wq*32 + 4*(l >> 5);
    float* ob = out + ((size_t)bt*256 + pr0)*256 + colb;
    #define EPI(ACC, CT)                                                       \
        do {                                                                   \
            const float bb_ = b1[colb + (CT)*32];                              \
            _Pragma("unroll")                                                  \
            for (int r_ = 0; r_ < 16; ++r_) {                                  \
                const int rr_ = (r_ & 3) + 8*(r_ >> 2);                        \
                __builtin_nontemporal_store(fmaxf(ACC[r_] + bb_, 0.f),         \
                    ob + (size_t)rr_*256 + (CT)*32);                           \
            }                                                                  \
        } while (0)
    EPI(acc0, 0);
    EPI(acc1, 1);
    EPI(acc2, 2);
    EPI(acc3, 3);
    #undef EPI
}

// ---------------------------------------------------------------------------
extern "C" void kernel_launch(void* const* d_in, const int* in_sizes, int n_in,
                              void* d_out, int out_size, void* d_ws, size_t ws_size,
                              hipStream_t stream) {
    const float* O  = (const float*)d_in[0];
    const float* W0 = (const float*)d_in[1];
    const float* b0 = (const float*)d_in[2];
    const float* W1 = (const float*)d_in[3];
    const float* b1 = (const float*)d_in[4];
    float* out = (float*)d_out;
    char* ws = (char*)d_ws;

    k_prep<<<1728, 256, 0, stream>>>(W0, W1, O, ws);
    dim3 guv(88, 4);
    k_uv<<<guv, 256, 0, stream>>>(ws, b0);
    k_obj<<<NBT, 256, 0, stream>>>(O, out);
    k_e<<<NBT * 4, 256, 0, stream>>>(ws, b1, out);
}

// Round 12
// 65.247 us; speedup vs baseline: 2.1616x; 1.0033x over previous
//
#include <hip/hip_runtime.h>
#include <hip/hip_bf16.h>

#define B_    32
#define T_    12
#define TM1   11
#define K_    16
#define DIM_  512
#define H0_   512
#define H1_   256
#define NROWS 5632
#define NBT   352
#define E_ELEMS (NBT*256*H1_)

typedef __bf16 bf16x8 __attribute__((ext_vector_type(8)));
typedef float  f32x16 __attribute__((ext_vector_type(16)));
typedef float  f32x4  __attribute__((ext_vector_type(4)));
typedef float  f32x2  __attribute__((ext_vector_type(2)));
typedef unsigned u32x4 __attribute__((ext_vector_type(4)));

#define OFRAG_OFF   0
#define W0FRAG_OFF  5767168
#define W1FRAG_OFF  (W0FRAG_OFF + 1048576)
#define UB_OFF      (W1FRAG_OFF + 262144)
#define VSW_OFF     (UB_OFF + 5767168)

__device__ __forceinline__ unsigned bf_rn(float f) {
    unsigned u = __float_as_uint(f);
    return (u + 0x7fffu + ((u >> 16) & 1u)) >> 16;
}
__device__ __forceinline__ unsigned pk_bf16(float lo, float hi) {
    return bf_rn(lo) | (bf_rn(hi) << 16);
}
__device__ __forceinline__ unsigned short f2bf(float f) {
    return (unsigned short)bf_rn(f);
}
__device__ __forceinline__ float bfu_lo(unsigned u) { return __uint_as_float(u << 16); }
__device__ __forceinline__ float bfu_hi(unsigned u) { return __uint_as_float(u & 0xffff0000u); }
// async global->LDS, 16B per lane, no VGPR round-trip
__device__ __forceinline__ void gl2lds16(const char* g, char* l) {
    __builtin_amdgcn_global_load_lds(
        (const __attribute__((address_space(1))) unsigned*)(const void*)g,
        (__attribute__((address_space(3))) unsigned*)(void*)l, 16, 0, 0);
}

// ---------------------------------------------------------------------------
// k_prep: merged W0/W1/O fragment repack (bf16, fragment-ordered).
// ---------------------------------------------------------------------------
__global__ __launch_bounds__(256) void k_prep(const float* __restrict__ W0,
                                              const float* __restrict__ W1,
                                              const float* __restrict__ O,
                                              char* __restrict__ ws)
{
    const int unit = blockIdx.x * 4 + (threadIdx.x >> 6);
    const int l = threadIdx.x & 63;
    if (unit < 1280) {
        const float* src; size_t dstoff; int stride;
        if (unit < 1024) {
            int half = unit >> 9, s = (unit >> 4) & 31, nt = unit & 15;
            int k = s*16 + (l >> 5)*8;
            int n = nt*32 + (l & 31);
            src = W0 + (size_t)(half*512 + k) * H0_ + n;
            stride = H0_;
            dstoff = W0FRAG_OFF + (((size_t)(half*32 + s)*16 + nt)*64 + l)*16;
        } else {
            int r = unit - 1024; int s = r >> 3, ct = r & 7;
            int k = s*16 + (l >> 5)*8;
            int n = ct*32 + (l & 31);
            src = W1 + (size_t)k * H1_ + n;
            stride = H1_;
            dstoff = W1FRAG_OFF + (((size_t)(s*8 + ct))*64 + l)*16;
        }
        float f[8];
        #pragma unroll
        for (int j = 0; j < 8; ++j) f[j] = src[(size_t)j * stride];
        u32x4 o = { pk_bf16(f[0],f[1]), pk_bf16(f[2],f[3]), pk_bf16(f[4],f[5]), pk_bf16(f[6],f[7]) };
        *(u32x4*)(ws + dstoff) = o;
    } else {
        const int u = unit - 1280;
        const int s = u / 176, mt = u % 176;
        const int row = mt*32 + (l & 31);
        const int b  = row / (TM1*K_);
        const int rem = row % (TM1*K_);
        const int t  = rem / K_;
        const int i  = rem % K_;
        const float* src = O + (((size_t)(b*T_ + t + 1)*K_ + i)*DIM_) + s*16 + (l >> 5)*8;
        float4 a = *(const float4*)src;
        float4 c = *(const float4*)(src + 4);
        u32x4 o = { pk_bf16(a.x,a.y), pk_bf16(a.z,a.w), pk_bf16(c.x,c.y), pk_bf16(c.z,c.w) };
        *(u32x4*)(ws + OFRAG_OFF + ((size_t)(s*176 + mt)*64 + l)*16) = o;
    }
}

// ---------------------------------------------------------------------------
// k_uv (unchanged)
// ---------------------------------------------------------------------------
__global__ __launch_bounds__(256) void k_uv(char* __restrict__ ws,
                                            const float* __restrict__ b0)
{
    const int mb = blockIdx.x;
    const int t  = threadIdx.x, l = t & 63;
    const int nb = blockIdx.y * 4 + (t >> 6);
    const int half = nb >> 3;
    const char* Ag = ws + OFRAG_OFF + ((size_t)(mb*2)*64 + l)*16;
    const char* Bg = ws + W0FRAG_OFF + (size_t)half*524288 + ((size_t)((nb&7)*2)*64 + l)*16;
    const size_t AS = 176*1024, BS = 16*1024;

    f32x16 acc[2][2];
    #pragma unroll
    for (int p = 0; p < 2; ++p)
        #pragma unroll
        for (int c = 0; c < 2; ++c)
            #pragma unroll
            for (int r = 0; r < 16; ++r) acc[p][c][r] = 0.f;

    u32x4 aA[2], bA[2], aB[2], bB[2];
    #pragma unroll
    for (int p = 0; p < 2; ++p) {
        aA[p] = *(const u32x4*)(Ag + 0*AS + p*1024);
        bA[p] = *(const u32x4*)(Bg + 0*BS + p*1024);
        aB[p] = *(const u32x4*)(Ag + 1*AS + p*1024);
        bB[p] = *(const u32x4*)(Bg + 1*BS + p*1024);
    }

    for (int ss = 0; ss < 32; ss += 2) {
        {
            union { u32x4 u[2]; bf16x8 b[2]; } af, bf;
            af.u[0]=aA[0]; af.u[1]=aA[1]; bf.u[0]=bA[0]; bf.u[1]=bA[1];
            if (ss + 2 < 32) {
                #pragma unroll
                for (int p = 0; p < 2; ++p) {
                    aA[p] = *(const u32x4*)(Ag + (size_t)(ss+2)*AS + p*1024);
                    bA[p] = *(const u32x4*)(Bg + (size_t)(ss+2)*BS + p*1024);
                }
            }
            acc[0][0] = __builtin_amdgcn_mfma_f32_32x32x16_bf16(af.b[0], bf.b[0], acc[0][0], 0,0,0);
            acc[0][1] = __builtin_amdgcn_mfma_f32_32x32x16_bf16(af.b[0], bf.b[1], acc[0][1], 0,0,0);
            acc[1][0] = __builtin_amdgcn_mfma_f32_32x32x16_bf16(af.b[1], bf.b[0], acc[1][0], 0,0,0);
            acc[1][1] = __builtin_amdgcn_mfma_f32_32x32x16_bf16(af.b[1], bf.b[1], acc[1][1], 0,0,0);
        }
        {
            union { u32x4 u[2]; bf16x8 b[2]; } af, bf;
            af.u[0]=aB[0]; af.u[1]=aB[1]; bf.u[0]=bB[0]; bf.u[1]=bB[1];
            if (ss + 3 < 32) {
                #pragma unroll
                for (int p = 0; p < 2; ++p) {
                    aB[p] = *(const u32x4*)(Ag + (size_t)(ss+3)*AS + p*1024);
                    bB[p] = *(const u32x4*)(Bg + (size_t)(ss+3)*BS + p*1024);
                }
            }
            acc[0][0] = __builtin_amdgcn_mfma_f32_32x32x16_bf16(af.b[0], bf.b[0], acc[0][0], 0,0,0);
            acc[0][1] = __builtin_amdgcn_mfma_f32_32x32x16_bf16(af.b[0], bf.b[1], acc[0][1], 0,0,0);
            acc[1][0] = __builtin_amdgcn_mfma_f32_32x32x16_bf16(af.b[1], bf.b[0], acc[1][0], 0,0,0);
            acc[1][1] = __builtin_amdgcn_mfma_f32_32x32x16_bf16(af.b[1], bf.b[1], acc[1][1], 0,0,0);
        }
    }

    #pragma unroll
    for (int p = 0; p < 2; ++p) {
        #pragma unroll
        for (int c = 0; c < 2; ++c) {
            const int col = (nb & 7)*64 + c*32 + (l & 31);
            const float bias = (half == 0) ? b0[col] : 0.f;
            #pragma unroll
            for (int r = 0; r < 16; ++r) {
                const int row = (r & 3) + 8*(r >> 2) + 4*(l >> 5);
                const int M = mb*64 + p*32 + row;
                const float v = acc[p][c][r] + bias;
                if (half == 0) {
                    *(unsigned short*)(ws + UB_OFF + ((size_t)M*512 + col)*2) = f2bf(v);
                } else {
                    const int bt = M >> 4, j = M & 15;
                    const int cc = col >> 3;
                    const int c2 = ((cc ^ (j & 7)) << 3) | (col & 7);
                    *(unsigned short*)(ws + VSW_OFF + ((size_t)(bt*16 + j)*512 + c2)*2) = f2bf(v);
                }
            }
        }
    }
}

// ---------------------------------------------------------------------------
// k_obj (unchanged)
// ---------------------------------------------------------------------------
__global__ __launch_bounds__(256) void k_obj(const float* __restrict__ O,
                                             float* __restrict__ out)
{
    __shared__ float red[16][16];
    __shared__ float fl[16];
    const int bt = blockIdx.x;
    const int b_ = bt / TM1, tt = bt % TM1;
    const int t  = threadIdx.x;
    const int i  = t >> 4, s = t & 15;
    const float* base = O + (((size_t)(b_ * T_ + tt + 1) * K_ + i) * DIM_) + s * 32;
    float sum = 0.f;
    #pragma unroll
    for (int q = 0; q < 8; ++q) {
        float4 v = *(const float4*)(base + q * 4);
        sum += v.x + v.y + v.z + v.w;
    }
    red[i][s] = sum;
    __syncthreads();
    if (t < 16) {
        float f = 0.f;
        #pragma unroll
        for (int s2 = 0; s2 < 16; ++s2) f += red[t][s2];
        fl[t] = fminf(fmaxf(f, 0.f), 1.f);
    }
    __syncthreads();
    const float val = fminf((float)(tt + 1) * fl[t >> 4] * fl[t & 15], 1.f);
    __builtin_nontemporal_store(val, out + (size_t)E_ELEMS + (size_t)bt * 256 + t);
}

// ---------------------------------------------------------------------------
// k_e v5: v4 structure (LDS-staged W1, global_load_lds, dbuf) with the h-build
// rewritten in plain C++: native __bf16 casts (compiler emits/fuses cvt_pk —
// T12/m240: inline-asm cvt_pk is -37%) and f32x2 packed add/max (v_pk_*_f32).
// ---------------------------------------------------------------------------
#define WSTAGE(C, BUFOFF)                                                      \
    do {                                                                       \
        gl2lds16(Wsrc + (size_t)((C)*2 + 0)*8192, Wbuf + (BUFOFF) + wq*1024);  \
        gl2lds16(Wsrc + (size_t)((C)*2 + 1)*8192, Wbuf + (BUFOFF) + 4096 + wq*1024); \
    } while (0)

#define KSTEP_L(S, BUFOFF, ST)                                                 \
    do {                                                                       \
        const int vch_ = (((S)*2 + kc) ^ jlow_);                               \
        u32x4 vu_ = *(const u32x4*)(VsL + vch_*16);                            \
        u32x4 uu_ = *(const u32x4*)(UsL + (S)*32);                             \
        bf16x8 af_;                                                            \
        _Pragma("unroll")                                                      \
        for (int q_ = 0; q_ < 4; ++q_) {                                       \
            f32x2 u2_ = { bfu_lo(uu_[q_]), bfu_hi(uu_[q_]) };                  \
            f32x2 v2_ = { bfu_lo(vu_[q_]), bfu_hi(vu_[q_]) };                  \
            f32x2 s2_ = u2_ + v2_;                                             \
            af_[2*q_]   = (__bf16)fmaxf(s2_.x, 0.f);                           \
            af_[2*q_+1] = (__bf16)fmaxf(s2_.y, 0.f);                           \
        }                                                                      \
        union { u32x4 u[4]; bf16x8 b[4]; } wu_;                                \
        _Pragma("unroll")                                                      \
        for (int c_ = 0; c_ < 4; ++c_)                                         \
            wu_.u[c_] = *(const u32x4*)(WlL + (BUFOFF) + (ST)*4096 + c_*1024); \
        acc0 = __builtin_amdgcn_mfma_f32_32x32x16_bf16(af_, wu_.b[0], acc0, 0,0,0); \
        acc1 = __builtin_amdgcn_mfma_f32_32x32x16_bf16(af_, wu_.b[1], acc1, 0,0,0); \
        acc2 = __builtin_amdgcn_mfma_f32_32x32x16_bf16(af_, wu_.b[2], acc2, 0,0,0); \
        acc3 = __builtin_amdgcn_mfma_f32_32x32x16_bf16(af_, wu_.b[3], acc3, 0,0,0); \
    } while (0)

__global__ __launch_bounds__(256, 3) void k_e(const char* __restrict__ ws,
                                              const float* __restrict__ b1,
                                              float* __restrict__ out)
{
    __shared__ alignas(16) char lds[40960];
    char* Us   = lds;                 // [8][512] bf16
    char* Vs   = lds + 8192;          // [16][512] bf16 (chunk-XOR content)
    char* Wbuf = lds + 24576;         // 2 x 8KB W1 chunk double-buffer

    const int bid = blockIdx.x;       // ((bt*2 + ph)*2 + ch)
    const int ch = bid & 1, ph = (bid >> 1) & 1, bt = bid >> 2;
    const int t = threadIdx.x, l = t & 63, wq = t >> 6;

    const char* Ug = ws + UB_OFF  + (size_t)(bt*16 + ph*8) * 1024;
    const char* Vg = ws + VSW_OFF + (size_t)bt * 16384;
    const char* Wsrc = ws + W1FRAG_OFF + (size_t)ch*4096 + (size_t)wq*1024 + (size_t)l*16;

    #pragma unroll
    for (int r = 0; r < 2; ++r) { int c = t + r*256; *(u32x4*)(Us + c*16) = *(const u32x4*)(Ug + c*16); }
    #pragma unroll
    for (int r = 0; r < 4; ++r) { int c = t + r*256; *(u32x4*)(Vs + c*16) = *(const u32x4*)(Vg + c*16); }

    // prologue: stage chunk 0 into buf0 (drained by the syncthreads below)
    WSTAGE(0, 0);
    __syncthreads();

    f32x16 acc0, acc1, acc2, acc3;
    #pragma unroll
    for (int r = 0; r < 16; ++r) { acc0[r] = 0.f; acc1[r] = 0.f; acc2[r] = 0.f; acc3[r] = 0.f; }

    const int jj    = l & 15;
    const int jlow_ = jj & 7;
    const int kc    = l >> 5;
    const int il    = wq*2 + ((l >> 4) & 1);
    const char* UsL = Us + il*1024 + kc*16;
    const char* VsL = Vs + jj*1024;
    const char* WlL = Wbuf + (size_t)l*16;

    for (int j = 0; j < 8; ++j) {
        const int c0 = j*2;                // chunk index in buf0
        if (c0 + 1 < 16) WSTAGE(c0+1, 8192);
        KSTEP_L(c0*2+0, 0, 0);
        KSTEP_L(c0*2+1, 0, 1);
        __syncthreads();                   // drains buf1 loads (in flight during compute)
        if (c0 + 2 < 16) WSTAGE(c0+2, 0);
        KSTEP_L(c0*2+2, 8192, 0);
        KSTEP_L(c0*2+3, 8192, 1);
        __syncthreads();
    }

    // epilogue: + b1, relu, nt scalar stores
    const int colb = ch*128 + (l & 31);
    const int pr0  = ph*128 + wq*32 + 4*(l >> 5);
    float* ob = out + ((size_t)bt*256 + pr0)*256 + colb;
    #define EPI(ACC, CT)                                                       \
        do {                                                                   \
            const float bb_ = b1[colb + (CT)*32];                              \
            _Pragma("unroll")                                                  \
            for (int r_ = 0; r_ < 16; ++r_) {                                  \
                const int rr_ = (r_ & 3) + 8*(r_ >> 2);                        \
                __builtin_nontemporal_store(fmaxf(ACC[r_] + bb_, 0.f),         \
                    ob + (size_t)rr_*256 + (CT)*32);                           \
            }                                                                  \
        } while (0)
    EPI(acc0, 0);
    EPI(acc1, 1);
    EPI(acc2, 2);
    EPI(acc3, 3);
    #undef EPI
}

// ---------------------------------------------------------------------------
extern "C" void kernel_launch(void* const* d_in, const int* in_sizes, int n_in,
                              void* d_out, int out_size, void* d_ws, size_t ws_size,
                              hipStream_t stream) {
    const float* O  = (const float*)d_in[0];
    const float* W0 = (const float*)d_in[1];
    const float* b0 = (const float*)d_in[2];
    const float* W1 = (const float*)d_in[3];
    const float* b1 = (const float*)d_in[4];
    float* out = (float*)d_out;
    char* ws = (char*)d_ws;

    k_prep<<<1728, 256, 0, stream>>>(W0, W1, O, ws);
    dim3 guv(88, 4);
    k_uv<<<guv, 256, 0, stream>>>(ws, b0);
    k_obj<<<NBT, 256, 0, stream>>>(O, out);
    k_e<<<NBT * 4, 256, 0, stream>>>(ws, b1, out);
}